// Round 1
// baseline (2058.559 us; speedup 1.0000x reference)
//
#include <hip/hip_runtime.h>
#include <hip/hip_bf16.h>

// ---------------------------------------------------------------------------
// QLenet forward, exact-math strategy:
//   All fq() outputs are e5m2 grid values (<=3 significant bits). Products of
//   two grid values have <=6-bit mantissas; sums of <=400 such products are
//   EXACT in f64 (order-independent). So f64 accumulation + f64 quantization
//   bitwise-matches a float64 numpy reference everywhere except ~1ulp effects
//   in BN variance (negligible tie risk). Intermediates stored as bf16
//   (grid values are exactly representable in bf16).
// ---------------------------------------------------------------------------

#define BATCH 8192

// fq: round to FP(e5m2) nearest-even, subnormals at 2^-16 grid, clip +-57344.
__device__ __forceinline__ double fq_d(double x) {
    double ax = fabs(x);
    if (!(ax > 0.0)) return x;            // preserves +-0 (and NaN) like the ref
    long long b = __double_as_longlong(ax);
    int fe = (int)(b >> 52) - 1023;       // floor(log2(ax)) for normal doubles
    if (fe < -14) fe = -14;               // subnormal clamp (EMIN)
    double scale = __longlong_as_double((long long)(fe - 2 + 1023) << 52); // 2^(fe-2)
    double q = rint(x / scale) * scale;   // half-to-even; exact ops (pow2 scale)
    q = fmin(fmax(q, -57344.0), 57344.0);
    return q;
}

// ---------------- weight quantization ----------------
__global__ void kquant(const float* __restrict__ in, float* __restrict__ out, int n) {
    int i = blockIdx.x * 256 + threadIdx.x;
    if (i < n) out[i] = (float)fq_d((double)in[i]);
}

// ---------------- conv1: [B,1,32,32] -> fq(conv) -> [B,6,28,28] ----------------
__global__ __launch_bounds__(256) void kconv1(const float* __restrict__ x,
        const float* __restrict__ qw, __hip_bfloat16* __restrict__ c1) {
    __shared__ float sx[1024];
    __shared__ float sw[152];
    int b = blockIdx.x, t = threadIdx.x;
    for (int i = t; i < 1024; i += 256) sx[i] = (float)fq_d((double)x[(size_t)b * 1024 + i]);
    if (t < 150) sw[t] = qw[t];
    __syncthreads();
    for (int o = t; o < 4704; o += 256) {
        int co = o / 784, p = o % 784;
        int i0 = p / 28, j0 = p % 28;
        const float* wp = &sw[co * 25];
        double acc = 0.0;
        #pragma unroll
        for (int u = 0; u < 5; ++u) {
            #pragma unroll
            for (int v = 0; v < 5; ++v)
                acc += (double)sx[(i0 + u) * 32 + (j0 + v)] * (double)wp[u * 5 + v];
        }
        c1[(size_t)b * 4704 + o] = __float2bfloat16((float)fq_d(acc));
    }
}

// ---------------- per-channel sum / sumsq over [B,C,HW] ----------------
__global__ __launch_bounds__(256) void kstats(const __hip_bfloat16* __restrict__ d,
        double* __restrict__ st, int C, int HW, int B) {
    int c = blockIdx.x, t = threadIdx.x;
    double s = 0.0, s2 = 0.0;
    for (int b = blockIdx.y; b < B; b += gridDim.y) {
        const __hip_bfloat16* row = d + ((size_t)b * C + c) * HW;
        for (int i = t; i < HW; i += 256) {
            double v = (double)__bfloat162float(row[i]);
            s += v; s2 += v * v;
        }
    }
    __shared__ double red[256];
    red[t] = s; __syncthreads();
    for (int stp = 128; stp > 0; stp >>= 1) { if (t < stp) red[t] += red[t + stp]; __syncthreads(); }
    if (t == 0) atomicAdd(&st[2 * c], red[0]);
    __syncthreads();
    red[t] = s2; __syncthreads();
    for (int stp = 128; stp > 0; stp >>= 1) { if (t < stp) red[t] += red[t + stp]; __syncthreads(); }
    if (t == 0) atomicAdd(&st[2 * c + 1], red[0]);
}

// ---------------- finalize BN: m, rsqrt(v+eps) ----------------
__global__ void kfinal(const double* __restrict__ st, double* __restrict__ mr, int C, double N) {
    int c = threadIdx.x;
    if (c < C) {
        double m = st[2 * c] / N;
        double v = st[2 * c + 1] / N - m * m;
        mr[2 * c] = m;
        mr[2 * c + 1] = 1.0 / sqrt(v + 1e-5);
    }
}

// ---------------- bn + fq + relu + 2x2 maxpool ----------------
__global__ __launch_bounds__(256) void kbnpool(const __hip_bfloat16* __restrict__ cin,
        const double* __restrict__ mr, const float* __restrict__ g, const float* __restrict__ be,
        __hip_bfloat16* __restrict__ pout, int C, int H, int W, int total) {
    int idx = blockIdx.x * 256 + threadIdx.x;
    if (idx >= total) return;
    int Ho = H >> 1, Wo = W >> 1;
    int wo = idx % Wo; int t1 = idx / Wo;
    int ho = t1 % Ho;  int t2 = t1 / Ho;
    int c = t2 % C;    int b = t2 / C;
    double m = mr[2 * c], r = mr[2 * c + 1];
    double gg = (double)g[c], bb = (double)be[c];
    const __hip_bfloat16* base = cin + (((size_t)b * C + c) * H + 2 * ho) * W + 2 * wo;
    float best = 0.0f;   // relu(fq(v)) then max == max(0, fq(v)...)
    #pragma unroll
    for (int dy = 0; dy < 2; ++dy) {
        #pragma unroll
        for (int dx = 0; dx < 2; ++dx) {
            double v = (double)__bfloat162float(base[dy * W + dx]);
            double q = fq_d(((v - m) * r) * gg + bb);
            best = fmaxf(best, (float)q);
        }
    }
    pout[idx] = __float2bfloat16(best);
}

// ---------------- conv2: [B,6,14,14] -> fq(conv) -> [B,16,10,10] ----------------
__global__ __launch_bounds__(256) void kconv2(const __hip_bfloat16* __restrict__ p1,
        const float* __restrict__ qw, __hip_bfloat16* __restrict__ c2) {
    __shared__ float sx[1176];
    __shared__ float sw[2400];
    int b = blockIdx.x, t = threadIdx.x;
    for (int i = t; i < 1176; i += 256) sx[i] = __bfloat162float(p1[(size_t)b * 1176 + i]);
    for (int i = t; i < 2400; i += 256) sw[i] = qw[i];
    __syncthreads();
    for (int o = t; o < 1600; o += 256) {
        int co = o / 100, p = o % 100;
        int i0 = p / 10, j0 = p % 10;
        const float* wb = &sw[co * 150];
        double acc = 0.0;
        for (int ci = 0; ci < 6; ++ci) {
            const float* xp = &sx[ci * 196 + i0 * 14 + j0];
            const float* wc = &wb[ci * 25];
            #pragma unroll
            for (int u = 0; u < 5; ++u) {
                #pragma unroll
                for (int v = 0; v < 5; ++v)
                    acc += (double)xp[u * 14 + v] * (double)wc[u * 5 + v];
            }
        }
        c2[(size_t)b * 1600 + o] = __float2bfloat16((float)fq_d(acc));
    }
}

// ---------------- qlinear: out = [relu?] fq( fq(x)@fq(W)^T + fq(b) ) ----------------
__global__ __launch_bounds__(256) void klinear(const __hip_bfloat16* __restrict__ X,
        const float* __restrict__ W, const float* __restrict__ bias,
        __hip_bfloat16* __restrict__ outb, float* __restrict__ outf,
        int B, int IN, int OUT, int do_relu) {
    int idx = blockIdx.x * 256 + threadIdx.x;
    if (idx >= B * OUT) return;
    int o = idx % OUT, b = idx / OUT;
    const __hip_bfloat16* xp = X + (size_t)b * IN;
    const float* wp = W + (size_t)o * IN;
    double acc = (double)bias[o];   // exact sum -> order-independent
    for (int k = 0; k < IN; ++k)
        acc += (double)__bfloat162float(xp[k]) * (double)wp[k];
    double q = fq_d(acc);
    if (do_relu && q < 0.0) q = 0.0;
    if (outf) outf[idx] = (float)q;
    else      outb[idx] = __float2bfloat16((float)q);
}

// ---------------------------------------------------------------------------
extern "C" void kernel_launch(void* const* d_in, const int* in_sizes, int n_in,
                              void* d_out, int out_size, void* d_ws, size_t ws_size,
                              hipStream_t stream) {
    const float* x   = (const float*)d_in[0];
    const float* w1  = (const float*)d_in[1];
    const float* g1  = (const float*)d_in[2];
    const float* be1 = (const float*)d_in[3];
    const float* w2  = (const float*)d_in[4];
    const float* g2  = (const float*)d_in[5];
    const float* be2 = (const float*)d_in[6];
    const float* fw1 = (const float*)d_in[7];
    const float* fb1 = (const float*)d_in[8];
    const float* fw2 = (const float*)d_in[9];
    const float* fb2 = (const float*)d_in[10];
    const float* fw3 = (const float*)d_in[11];
    const float* fb3 = (const float*)d_in[12];

    char* ws = (char*)d_ws;
    // small region
    double* stats1 = (double*)(ws + 0);      // 12 dbl
    double* mr1    = (double*)(ws + 256);    // 12 dbl
    double* stats2 = (double*)(ws + 512);    // 32 dbl
    double* mr2    = (double*)(ws + 768);    // 32 dbl
    float* qw1  = (float*)(ws + 1024);       // 150
    float* qw2  = (float*)(ws + 2048);       // 2400
    float* qfw1 = (float*)(ws + 12288);      // 48000 (ends 204288)
    float* qfb1 = (float*)(ws + 204544);     // 120
    float* qfw2 = (float*)(ws + 205056);     // 10080 (ends 245376)
    float* qfb2 = (float*)(ws + 245504);     // 84
    float* qfw3 = (float*)(ws + 245888);     // 840
    float* qfb3 = (float*)(ws + 249344);     // 10
    // big buffers (aliased by liveness)
    __hip_bfloat16* bufA = (__hip_bfloat16*)(ws + 249856);    // c1 (77,070,336 B) then c2
    __hip_bfloat16* bufB = (__hip_bfloat16*)(ws + 77320192);  // p1 (19,267,584 B) then p2
    __hip_bfloat16* bufC = (__hip_bfloat16*)(ws + 96587776);  // a1 (1,966,080 B)
    __hip_bfloat16* bufD = (__hip_bfloat16*)(ws + 98553856);  // a2 (1,376,256 B)

    // zero BN accumulators
    hipMemsetAsync(ws, 0, 1024, stream);

    // quantize all weights/biases
    kquant<<<1, 256, 0, stream>>>(w1, qw1, 150);
    kquant<<<(2400 + 255) / 256, 256, 0, stream>>>(w2, qw2, 2400);
    kquant<<<(48000 + 255) / 256, 256, 0, stream>>>(fw1, qfw1, 48000);
    kquant<<<1, 256, 0, stream>>>(fb1, qfb1, 120);
    kquant<<<(10080 + 255) / 256, 256, 0, stream>>>(fw2, qfw2, 10080);
    kquant<<<1, 256, 0, stream>>>(fb2, qfb2, 84);
    kquant<<<(840 + 255) / 256, 256, 0, stream>>>(fw3, qfw3, 840);
    kquant<<<1, 256, 0, stream>>>(fb3, qfb3, 10);

    // conv1 + fq  -> bufA [B,6,28,28]
    kconv1<<<BATCH, 256, 0, stream>>>(x, qw1, bufA);
    // bn1 stats
    kstats<<<dim3(6, 256), 256, 0, stream>>>(bufA, stats1, 6, 784, BATCH);
    kfinal<<<1, 32, 0, stream>>>(stats1, mr1, 6, (double)BATCH * 784.0);
    // bn1 + fq + relu + pool -> bufB [B,6,14,14]
    {
        int total = BATCH * 6 * 14 * 14;
        kbnpool<<<(total + 255) / 256, 256, 0, stream>>>(bufA, mr1, g1, be1, bufB, 6, 28, 28, total);
    }
    // conv2 + fq -> bufA [B,16,10,10]
    kconv2<<<BATCH, 256, 0, stream>>>(bufB, qw2, bufA);
    // bn2 stats
    kstats<<<dim3(16, 256), 256, 0, stream>>>(bufA, stats2, 16, 100, BATCH);
    kfinal<<<1, 32, 0, stream>>>(stats2, mr2, 16, (double)BATCH * 100.0);
    // bn2 + fq + relu + pool -> bufB [B,16,5,5] == [B,400]
    {
        int total = BATCH * 16 * 5 * 5;
        kbnpool<<<(total + 255) / 256, 256, 0, stream>>>(bufA, mr2, g2, be2, bufB, 16, 10, 10, total);
    }
    // fc1 (+relu) -> bufC [B,120]
    {
        long long tot = (long long)BATCH * 120;
        klinear<<<(int)((tot + 255) / 256), 256, 0, stream>>>(bufB, qfw1, qfb1, bufC, (float*)nullptr, BATCH, 400, 120, 1);
    }
    // fc2 (+relu) -> bufD [B,84]
    {
        long long tot = (long long)BATCH * 84;
        klinear<<<(int)((tot + 255) / 256), 256, 0, stream>>>(bufC, qfw2, qfb2, bufD, (float*)nullptr, BATCH, 120, 84, 1);
    }
    // fc3 -> d_out [B,10] float
    {
        long long tot = (long long)BATCH * 10;
        klinear<<<(int)((tot + 255) / 256), 256, 0, stream>>>(bufD, qfw3, qfb3, (__hip_bfloat16*)nullptr, (float*)d_out, BATCH, 84, 10, 0);
    }
}

// Round 2
// 1147.317 us; speedup vs baseline: 1.7942x; 1.7942x over previous
//
#include <hip/hip_runtime.h>
#include <hip/hip_bf16.h>

// ---------------------------------------------------------------------------
// QLenet forward, exact-math strategy (see round-0 notes):
//   All fq() outputs are e5m2 grid values (<=3 significant bits). Products of
//   two grid values have <=6-bit mantissas; dot-product sums (<=400 terms,
//   bounded exponent span) are EXACT in f64 -> order-independent -> matches
//   the float64 numpy reference. Intermediates stored as bf16 (exact for grid
//   values).
// Round 1 -> 2: FC layers rewritten as tiled kernels (transposed quantized W,
//   coalesced global W loads, f64 X tile in LDS, 8 rows/thread f64 acc).
//   conv LDS promoted to f64 (pure v_fma_f64 inner loop).
// ---------------------------------------------------------------------------

#define BATCH 8192

// fq: round to FP(e5m2) nearest-even, subnormals at 2^-18 grid, clip +-57344.
__device__ __forceinline__ double fq_d(double x) {
    double ax = fabs(x);
    if (!(ax > 0.0)) return x;            // preserves +-0 (and NaN) like the ref
    long long b = __double_as_longlong(ax);
    int fe = (int)(b >> 52) - 1023;       // floor(log2(ax)) for normal doubles
    if (fe < -14) fe = -14;               // subnormal clamp (EMIN)
    double scale = __longlong_as_double((long long)(fe - 2 + 1023) << 52); // 2^(fe-2)
    double q = rint(x / scale) * scale;   // half-to-even; exact ops (pow2 scale)
    q = fmin(fmax(q, -57344.0), 57344.0);
    return q;
}

// ---------------- weight / bias quantization ----------------
__global__ void kquant(const float* __restrict__ in, float* __restrict__ out, int n) {
    int i = blockIdx.x * 256 + threadIdx.x;
    if (i < n) out[i] = (float)fq_d((double)in[i]);
}

// transpose + quantize: Wt[k*OUTP+o] = fq(W[o*IN+k]), zero-padded o>=OUT
__global__ void ktransq(const float* __restrict__ W, float* __restrict__ Wt,
                        int IN, int OUT, int OUTP, int n) {
    int i = blockIdx.x * 256 + threadIdx.x;
    if (i >= n) return;
    int k = i / OUTP, o = i % OUTP;
    Wt[i] = (o < OUT) ? (float)fq_d((double)W[o * IN + k]) : 0.0f;
}

// ---------------- conv1: [B,1,32,32] -> fq(conv) -> [B,6,28,28] ----------------
__global__ __launch_bounds__(256) void kconv1(const float* __restrict__ x,
        const float* __restrict__ qw, __hip_bfloat16* __restrict__ c1) {
    __shared__ double sx[1024];
    __shared__ double sw[152];
    int b = blockIdx.x, t = threadIdx.x;
    for (int i = t; i < 1024; i += 256) sx[i] = fq_d((double)x[(size_t)b * 1024 + i]);
    if (t < 150) sw[t] = (double)qw[t];
    __syncthreads();
    for (int o = t; o < 4704; o += 256) {
        int co = o / 784, p = o % 784;
        int i0 = p / 28, j0 = p % 28;
        const double* wp = &sw[co * 25];
        double acc = 0.0;
        #pragma unroll
        for (int u = 0; u < 5; ++u) {
            #pragma unroll
            for (int v = 0; v < 5; ++v)
                acc = fma(sx[(i0 + u) * 32 + (j0 + v)], wp[u * 5 + v], acc);
        }
        c1[(size_t)b * 4704 + o] = __float2bfloat16((float)fq_d(acc));
    }
}

// ---------------- per-channel sum / sumsq over [B,C,HW] ----------------
__global__ __launch_bounds__(256) void kstats(const __hip_bfloat16* __restrict__ d,
        double* __restrict__ st, int C, int HW, int B) {
    int c = blockIdx.x, t = threadIdx.x;
    double s = 0.0, s2 = 0.0;
    for (int b = blockIdx.y; b < B; b += gridDim.y) {
        const __hip_bfloat16* row = d + ((size_t)b * C + c) * HW;
        for (int i = t; i < HW; i += 256) {
            double v = (double)__bfloat162float(row[i]);
            s += v; s2 += v * v;
        }
    }
    __shared__ double red[256];
    red[t] = s; __syncthreads();
    for (int stp = 128; stp > 0; stp >>= 1) { if (t < stp) red[t] += red[t + stp]; __syncthreads(); }
    if (t == 0) atomicAdd(&st[2 * c], red[0]);
    __syncthreads();
    red[t] = s2; __syncthreads();
    for (int stp = 128; stp > 0; stp >>= 1) { if (t < stp) red[t] += red[t + stp]; __syncthreads(); }
    if (t == 0) atomicAdd(&st[2 * c + 1], red[0]);
}

// ---------------- finalize BN: m, rsqrt(v+eps) ----------------
__global__ void kfinal(const double* __restrict__ st, double* __restrict__ mr, int C, double N) {
    int c = threadIdx.x;
    if (c < C) {
        double m = st[2 * c] / N;
        double v = st[2 * c + 1] / N - m * m;
        mr[2 * c] = m;
        mr[2 * c + 1] = 1.0 / sqrt(v + 1e-5);
    }
}

// ---------------- bn + fq + relu + 2x2 maxpool ----------------
__global__ __launch_bounds__(256) void kbnpool(const __hip_bfloat16* __restrict__ cin,
        const double* __restrict__ mr, const float* __restrict__ g, const float* __restrict__ be,
        __hip_bfloat16* __restrict__ pout, int C, int H, int W, int total) {
    int idx = blockIdx.x * 256 + threadIdx.x;
    if (idx >= total) return;
    int Ho = H >> 1, Wo = W >> 1;
    int wo = idx % Wo; int t1 = idx / Wo;
    int ho = t1 % Ho;  int t2 = t1 / Ho;
    int c = t2 % C;    int b = t2 / C;
    double m = mr[2 * c], r = mr[2 * c + 1];
    double gg = (double)g[c], bb = (double)be[c];
    const __hip_bfloat16* base = cin + (((size_t)b * C + c) * H + 2 * ho) * W + 2 * wo;
    float best = 0.0f;   // relu(fq(v)) then max == max(0, fq(v)...)
    #pragma unroll
    for (int dy = 0; dy < 2; ++dy) {
        #pragma unroll
        for (int dx = 0; dx < 2; ++dx) {
            double v = (double)__bfloat162float(base[dy * W + dx]);
            double q = fq_d(((v - m) * r) * gg + bb);
            best = fmaxf(best, (float)q);
        }
    }
    pout[idx] = __float2bfloat16(best);
}

// ---------------- conv2: [B,6,14,14] -> fq(conv) -> [B,16,10,10] ----------------
__global__ __launch_bounds__(256) void kconv2(const __hip_bfloat16* __restrict__ p1,
        const float* __restrict__ qw, __hip_bfloat16* __restrict__ c2) {
    __shared__ double sx[1176];
    __shared__ double sw[2400];
    int b = blockIdx.x, t = threadIdx.x;
    for (int i = t; i < 1176; i += 256) sx[i] = (double)__bfloat162float(p1[(size_t)b * 1176 + i]);
    for (int i = t; i < 2400; i += 256) sw[i] = (double)qw[i];
    __syncthreads();
    for (int o = t; o < 1600; o += 256) {
        int co = o / 100, p = o % 100;
        int i0 = p / 10, j0 = p % 10;
        const double* wb = &sw[co * 150];
        double acc = 0.0;
        for (int ci = 0; ci < 6; ++ci) {
            const double* xp = &sx[ci * 196 + i0 * 14 + j0];
            const double* wc = &wb[ci * 25];
            #pragma unroll
            for (int u = 0; u < 5; ++u) {
                #pragma unroll
                for (int v = 0; v < 5; ++v)
                    acc = fma(xp[u * 14 + v], wc[u * 5 + v], acc);
            }
        }
        c2[(size_t)b * 1600 + o] = __float2bfloat16((float)fq_d(acc));
    }
}

// ---------------- tiled FC: out = [relu?] fq( X @ Wt + qb ) ----------------
// Wt: [IN][OUTP] f32 quantized, zero-padded. X: [B][IN] bf16.
// Block: 256 threads = GROUPS row-groups x OUTP output lanes; BT rows/block.
template<int IN, int OUT, int OUTP, int ROWS>
__global__ __launch_bounds__(256) void kfc(const __hip_bfloat16* __restrict__ X,
        const float* __restrict__ Wt, const float* __restrict__ qb,
        __hip_bfloat16* __restrict__ outb, float* __restrict__ outf, int do_relu) {
    constexpr int GROUPS = 256 / OUTP;
    constexpr int BT = ROWS * GROUPS;
    __shared__ double sx[BT][IN];
    int t = threadIdx.x;
    int b0 = blockIdx.x * BT;
    for (int i = t; i < BT * IN; i += 256) {
        int r = i / IN, k = i % IN;
        sx[r][k] = (double)__bfloat162float(X[(size_t)(b0 + r) * IN + k]);
    }
    __syncthreads();
    int o = t % OUTP;
    int g = t / OUTP;
    double acc[ROWS];
    double bias = (o < OUT) ? (double)qb[o] : 0.0;
    #pragma unroll
    for (int r = 0; r < ROWS; ++r) acc[r] = bias;
    #pragma unroll 4
    for (int k = 0; k < IN; ++k) {
        double w = (double)Wt[k * OUTP + o];   // coalesced, L2-resident
        #pragma unroll
        for (int r = 0; r < ROWS; ++r)
            acc[r] = fma(sx[g * ROWS + r][k], w, acc[r]);  // LDS broadcast reads
    }
    if (o < OUT) {
        #pragma unroll
        for (int r = 0; r < ROWS; ++r) {
            double q = fq_d(acc[r]);
            if (do_relu && q < 0.0) q = 0.0;
            size_t b = (size_t)(b0 + g * ROWS + r);
            if (outf) outf[b * OUT + o] = (float)q;
            else      outb[b * OUT + o] = __float2bfloat16((float)q);
        }
    }
}

// ---------------------------------------------------------------------------
extern "C" void kernel_launch(void* const* d_in, const int* in_sizes, int n_in,
                              void* d_out, int out_size, void* d_ws, size_t ws_size,
                              hipStream_t stream) {
    const float* x   = (const float*)d_in[0];
    const float* w1  = (const float*)d_in[1];
    const float* g1  = (const float*)d_in[2];
    const float* be1 = (const float*)d_in[3];
    const float* w2  = (const float*)d_in[4];
    const float* g2  = (const float*)d_in[5];
    const float* be2 = (const float*)d_in[6];
    const float* fw1 = (const float*)d_in[7];
    const float* fb1 = (const float*)d_in[8];
    const float* fw2 = (const float*)d_in[9];
    const float* fb2 = (const float*)d_in[10];
    const float* fw3 = (const float*)d_in[11];
    const float* fb3 = (const float*)d_in[12];

    char* ws = (char*)d_ws;
    double* stats1 = (double*)(ws + 0);      // 12 dbl
    double* mr1    = (double*)(ws + 256);    // 12 dbl
    double* stats2 = (double*)(ws + 512);    // 32 dbl
    double* mr2    = (double*)(ws + 768);    // 32 dbl
    float* qw1  = (float*)(ws + 1024);       // 150
    float* qw2  = (float*)(ws + 2048);       // 2400 (ends 11648)
    float* qfb1 = (float*)(ws + 12288);      // 120
    float* qfb2 = (float*)(ws + 12800);      // 84
    float* qfb3 = (float*)(ws + 13184);      // 10
    float* Wt1  = (float*)(ws + 16384);      // 400*128 (ends 221184)
    float* Wt2  = (float*)(ws + 221184);     // 120*128 (ends 282624)
    float* Wt3  = (float*)(ws + 282624);     // 84*16   (ends 288000)
    // big buffers (aliased by liveness)
    __hip_bfloat16* bufA = (__hip_bfloat16*)(ws + 294912);    // c1 [B,6,28,28] then c2 [B,16,10,10]
    __hip_bfloat16* bufB = (__hip_bfloat16*)(ws + 77365248);  // p1 [B,6,14,14] then p2 [B,400]
    __hip_bfloat16* bufC = (__hip_bfloat16*)(ws + 294912);    // a1 [B,120] (aliases dead bufA)
    __hip_bfloat16* bufD = (__hip_bfloat16*)(ws + 294912 + 2097152); // a2 [B,84]

    hipMemsetAsync(ws, 0, 1024, stream);

    // quantize conv weights + fc biases; transpose+quantize fc weights
    kquant<<<1, 256, 0, stream>>>(w1, qw1, 150);
    kquant<<<(2400 + 255) / 256, 256, 0, stream>>>(w2, qw2, 2400);
    kquant<<<1, 256, 0, stream>>>(fb1, qfb1, 120);
    kquant<<<1, 256, 0, stream>>>(fb2, qfb2, 84);
    kquant<<<1, 256, 0, stream>>>(fb3, qfb3, 10);
    ktransq<<<(51200 + 255) / 256, 256, 0, stream>>>(fw1, Wt1, 400, 120, 128, 51200);
    ktransq<<<(15360 + 255) / 256, 256, 0, stream>>>(fw2, Wt2, 120, 84, 128, 15360);
    ktransq<<<(1344 + 255) / 256, 256, 0, stream>>>(fw3, Wt3, 84, 10, 16, 1344);

    // conv1 + fq  -> bufA [B,6,28,28]
    kconv1<<<BATCH, 256, 0, stream>>>(x, qw1, bufA);
    kstats<<<dim3(6, 256), 256, 0, stream>>>(bufA, stats1, 6, 784, BATCH);
    kfinal<<<1, 32, 0, stream>>>(stats1, mr1, 6, (double)BATCH * 784.0);
    {
        int total = BATCH * 6 * 14 * 14;
        kbnpool<<<(total + 255) / 256, 256, 0, stream>>>(bufA, mr1, g1, be1, bufB, 6, 28, 28, total);
    }
    // conv2 + fq -> bufA [B,16,10,10]
    kconv2<<<BATCH, 256, 0, stream>>>(bufB, qw2, bufA);
    kstats<<<dim3(16, 256), 256, 0, stream>>>(bufA, stats2, 16, 100, BATCH);
    kfinal<<<1, 32, 0, stream>>>(stats2, mr2, 16, (double)BATCH * 100.0);
    {
        int total = BATCH * 16 * 5 * 5;
        kbnpool<<<(total + 255) / 256, 256, 0, stream>>>(bufA, mr2, g2, be2, bufB, 16, 10, 10, total);
    }
    // fc1 (+relu): [B,400] -> [B,120]
    kfc<400, 120, 128, 8><<<BATCH / 16, 256, 0, stream>>>(bufB, Wt1, qfb1, bufC, (float*)nullptr, 1);
    // fc2 (+relu): [B,120] -> [B,84]
    kfc<120, 84, 128, 8><<<BATCH / 16, 256, 0, stream>>>(bufC, Wt2, qfb2, bufD, (float*)nullptr, 1);
    // fc3: [B,84] -> [B,10] float out
    kfc<84, 10, 16, 1><<<BATCH / 16, 256, 0, stream>>>(bufD, Wt3, qfb3, (__hip_bfloat16*)nullptr, (float*)d_out, 0);
}

// Round 3
// 672.153 us; speedup vs baseline: 3.0626x; 1.7069x over previous
//
#include <hip/hip_runtime.h>
#include <hip/hip_bf16.h>

// ---------------------------------------------------------------------------
// QLenet forward, exact-math strategy (round-0 notes):
//   All fq() outputs are e5m2 grid values (<=3 significant bits). Products of
//   two grid values have <=6-bit mantissas; dot sums (<=400 terms, bounded
//   exponent span) are EXACT in f64 -> order-independent -> matches float64
//   numpy reference. Intermediates stored as bf16 (exact for grid values).
// Round 2 -> 3: convs register-tiled (thread owns an output row) to cut LDS
//   wave-instrs ~5x and kill 4-way f64 bank conflicts (conv1 x-tile padded to
//   stride 33; conv2 row reads are 10-distinct-address broadcasts).
// ---------------------------------------------------------------------------

#define BATCH 8192

__device__ __forceinline__ double fq_d(double x) {
    double ax = fabs(x);
    if (!(ax > 0.0)) return x;            // preserves +-0 like the ref
    long long b = __double_as_longlong(ax);
    int fe = (int)(b >> 52) - 1023;       // floor(log2(ax)) for normal doubles
    if (fe < -14) fe = -14;               // subnormal clamp (EMIN)
    double scale = __longlong_as_double((long long)(fe - 2 + 1023) << 52); // 2^(fe-2)
    double q = rint(x / scale) * scale;   // half-to-even; exact ops
    q = fmin(fmax(q, -57344.0), 57344.0);
    return q;
}

__device__ __forceinline__ unsigned short bfbits(double q) {
    __hip_bfloat16 h = __float2bfloat16((float)q);   // exact for grid values
    return *(unsigned short*)&h;
}

// ---------------- weight / bias quantization ----------------
__global__ void kquant(const float* __restrict__ in, float* __restrict__ out, int n) {
    int i = blockIdx.x * 256 + threadIdx.x;
    if (i < n) out[i] = (float)fq_d((double)in[i]);
}

// transpose + quantize: Wt[k*OUTP+o] = fq(W[o*IN+k]), zero-padded o>=OUT
__global__ void ktransq(const float* __restrict__ W, float* __restrict__ Wt,
                        int IN, int OUT, int OUTP, int n) {
    int i = blockIdx.x * 256 + threadIdx.x;
    if (i >= n) return;
    int k = i / OUTP, o = i % OUTP;
    Wt[i] = (o < OUT) ? (float)fq_d((double)W[o * IN + k]) : 0.0f;
}

// ---------------- conv1: [B,1,32,32] -> fq(conv) -> [B,6,28,28] ----------------
// 3 images/block; task = (img, co, i0) -> full 28-wide output row.
// x tile padded to stride 33 (stride-32 f64 would put all i0 lanes on 1 bank).
__global__ __launch_bounds__(256) void kconv1(const float* __restrict__ x,
        const float* __restrict__ qw, __hip_bfloat16* __restrict__ c1, int nimg_total) {
    __shared__ double sx[3 * 1056];   // 3 x (32 rows x 33)
    __shared__ double sw[152];
    int t = threadIdx.x;
    int b0 = blockIdx.x * 3;
    int nimg = nimg_total - b0; if (nimg > 3) nimg = 3;
    for (int i = t; i < nimg * 1024; i += 256) {
        int img = i >> 10, idx = i & 1023;
        int row = idx >> 5, col = idx & 31;
        sx[img * 1056 + row * 33 + col] = fq_d((double)x[(size_t)(b0 + img) * 1024 + idx]);
    }
    if (t < 150) sw[t] = (double)qw[t];
    __syncthreads();
    int ntask = nimg * 168;
    for (int task = t; task < ntask; task += 256) {
        int img = task / 168; int r = task % 168;
        int co = r / 28, i0 = r % 28;
        const double* xb = &sx[img * 1056];
        const double* wp = &sw[co * 25];
        double acc[28];
        #pragma unroll
        for (int j = 0; j < 28; ++j) acc[j] = 0.0;
        #pragma unroll
        for (int u = 0; u < 5; ++u) {
            const double* xr = &xb[(i0 + u) * 33];
            double w0 = wp[u*5], w1 = wp[u*5+1], w2 = wp[u*5+2], w3 = wp[u*5+3], w4 = wp[u*5+4];
            double xv[18];
            #pragma unroll
            for (int k = 0; k < 18; ++k) xv[k] = xr[k];
            #pragma unroll
            for (int j = 0; j < 14; ++j)
                acc[j] = fma(xv[j], w0, fma(xv[j+1], w1, fma(xv[j+2], w2,
                         fma(xv[j+3], w3, fma(xv[j+4], w4, acc[j])))));
            #pragma unroll
            for (int k = 0; k < 18; ++k) xv[k] = xr[14 + k];
            #pragma unroll
            for (int j = 0; j < 14; ++j)
                acc[14+j] = fma(xv[j], w0, fma(xv[j+1], w1, fma(xv[j+2], w2,
                            fma(xv[j+3], w3, fma(xv[j+4], w4, acc[14+j])))));
        }
        size_t base = ((size_t)(b0 + img) * 6 + co) * 784 + (size_t)i0 * 28;
        #pragma unroll
        for (int j = 0; j < 28; j += 4) {
            ushort4 pk;
            pk.x = bfbits(fq_d(acc[j+0])); pk.y = bfbits(fq_d(acc[j+1]));
            pk.z = bfbits(fq_d(acc[j+2])); pk.w = bfbits(fq_d(acc[j+3]));
            *(ushort4*)&c1[base + j] = pk;   // base % 4 == 0 -> 8B aligned
        }
    }
}

// ---------------- per-channel sum / sumsq over [B,C,HW] ----------------
__global__ __launch_bounds__(256) void kstats(const __hip_bfloat16* __restrict__ d,
        double* __restrict__ st, int C, int HW, int B) {
    int c = blockIdx.x, t = threadIdx.x;
    double s = 0.0, s2 = 0.0;
    for (int b = blockIdx.y; b < B; b += gridDim.y) {
        const __hip_bfloat16* row = d + ((size_t)b * C + c) * HW;
        for (int i = t; i < HW; i += 256) {
            double v = (double)__bfloat162float(row[i]);
            s += v; s2 += v * v;
        }
    }
    __shared__ double red[256];
    red[t] = s; __syncthreads();
    for (int stp = 128; stp > 0; stp >>= 1) { if (t < stp) red[t] += red[t + stp]; __syncthreads(); }
    if (t == 0) atomicAdd(&st[2 * c], red[0]);
    __syncthreads();
    red[t] = s2; __syncthreads();
    for (int stp = 128; stp > 0; stp >>= 1) { if (t < stp) red[t] += red[t + stp]; __syncthreads(); }
    if (t == 0) atomicAdd(&st[2 * c + 1], red[0]);
}

// ---------------- finalize BN: m, rsqrt(v+eps) ----------------
__global__ void kfinal(const double* __restrict__ st, double* __restrict__ mr, int C, double N) {
    int c = threadIdx.x;
    if (c < C) {
        double m = st[2 * c] / N;
        double v = st[2 * c + 1] / N - m * m;
        mr[2 * c] = m;
        mr[2 * c + 1] = 1.0 / sqrt(v + 1e-5);
    }
}

// ---------------- bn + fq + relu + 2x2 maxpool ----------------
__global__ __launch_bounds__(256) void kbnpool(const __hip_bfloat16* __restrict__ cin,
        const double* __restrict__ mr, const float* __restrict__ g, const float* __restrict__ be,
        __hip_bfloat16* __restrict__ pout, int C, int H, int W, int total) {
    int idx = blockIdx.x * 256 + threadIdx.x;
    if (idx >= total) return;
    int Ho = H >> 1, Wo = W >> 1;
    int wo = idx % Wo; int t1 = idx / Wo;
    int ho = t1 % Ho;  int t2 = t1 / Ho;
    int c = t2 % C;    int b = t2 / C;
    double m = mr[2 * c], r = mr[2 * c + 1];
    double gg = (double)g[c], bb = (double)be[c];
    const __hip_bfloat16* base = cin + (((size_t)b * C + c) * H + 2 * ho) * W + 2 * wo;
    float best = 0.0f;   // relu(fq(v)) then max == max(0, fq(v)...)
    #pragma unroll
    for (int dy = 0; dy < 2; ++dy) {
        #pragma unroll
        for (int dx = 0; dx < 2; ++dx) {
            double v = (double)__bfloat162float(base[dy * W + dx]);
            double q = fq_d(((v - m) * r) * gg + bb);
            best = fmaxf(best, (float)q);
        }
    }
    pout[idx] = __float2bfloat16(best);
}

// ---------------- conv2: [B,6,14,14] -> fq(conv) -> [B,16,10,10] ----------------
// 2 images/block, 320 threads; task = (img, co, i0) -> 10-wide output row.
__global__ __launch_bounds__(320) void kconv2(const __hip_bfloat16* __restrict__ p1,
        const float* __restrict__ qw, __hip_bfloat16* __restrict__ c2) {
    __shared__ double sx[2352];   // 2 x [6][14][14]
    __shared__ double sw[2400];   // [16][6][5][5]
    int t = threadIdx.x;
    int b0 = blockIdx.x * 2;
    for (int i = t; i < 2352; i += 320) sx[i] = (double)__bfloat162float(p1[(size_t)b0 * 1176 + i]);
    for (int i = t; i < 2400; i += 320) sw[i] = (double)qw[i];
    __syncthreads();
    int img = t / 160, r = t % 160;
    int co = r / 10, i0 = r % 10;
    const double* xb = &sx[img * 1176];
    const double* wb = &sw[co * 150];
    double acc[10];
    #pragma unroll
    for (int j = 0; j < 10; ++j) acc[j] = 0.0;
    for (int ci = 0; ci < 6; ++ci) {
        #pragma unroll
        for (int u = 0; u < 5; ++u) {
            const double* xr = &xb[ci * 196 + (i0 + u) * 14];   // even offset -> b128-able
            const double* wr = &wb[ci * 25 + u * 5];
            double xv[14];
            #pragma unroll
            for (int k = 0; k < 14; ++k) xv[k] = xr[k];
            double w0 = wr[0], w1 = wr[1], w2 = wr[2], w3 = wr[3], w4 = wr[4];
            #pragma unroll
            for (int j = 0; j < 10; ++j)
                acc[j] = fma(xv[j], w0, fma(xv[j+1], w1, fma(xv[j+2], w2,
                         fma(xv[j+3], w3, fma(xv[j+4], w4, acc[j])))));
        }
    }
    size_t base = ((size_t)(b0 + img) * 16 + co) * 100 + (size_t)i0 * 10;
    #pragma unroll
    for (int j = 0; j < 10; j += 2) {
        ushort2 pk;
        pk.x = bfbits(fq_d(acc[j])); pk.y = bfbits(fq_d(acc[j+1]));
        *(ushort2*)&c2[base + j] = pk;   // base even -> 4B aligned
    }
}

// ---------------- tiled FC: out = [relu?] fq( X @ Wt + qb ) ----------------
template<int IN, int OUT, int OUTP, int ROWS>
__global__ __launch_bounds__(256) void kfc(const __hip_bfloat16* __restrict__ X,
        const float* __restrict__ Wt, const float* __restrict__ qb,
        __hip_bfloat16* __restrict__ outb, float* __restrict__ outf, int do_relu) {
    constexpr int GROUPS = 256 / OUTP;
    constexpr int BT = ROWS * GROUPS;
    __shared__ double sx[BT][IN];
    int t = threadIdx.x;
    int b0 = blockIdx.x * BT;
    for (int i = t; i < BT * IN; i += 256) {
        int r = i / IN, k = i % IN;
        sx[r][k] = (double)__bfloat162float(X[(size_t)(b0 + r) * IN + k]);
    }
    __syncthreads();
    int o = t % OUTP;
    int g = t / OUTP;
    double acc[ROWS];
    double bias = (o < OUT) ? (double)qb[o] : 0.0;
    #pragma unroll
    for (int r = 0; r < ROWS; ++r) acc[r] = bias;
    #pragma unroll 4
    for (int k = 0; k < IN; ++k) {
        double w = (double)Wt[k * OUTP + o];   // coalesced, L2-resident
        #pragma unroll
        for (int r = 0; r < ROWS; ++r)
            acc[r] = fma(sx[g * ROWS + r][k], w, acc[r]);  // LDS broadcast reads
    }
    if (o < OUT) {
        #pragma unroll
        for (int r = 0; r < ROWS; ++r) {
            double q = fq_d(acc[r]);
            if (do_relu && q < 0.0) q = 0.0;
            size_t b = (size_t)(b0 + g * ROWS + r);
            if (outf) outf[b * OUT + o] = (float)q;
            else      outb[b * OUT + o] = __float2bfloat16((float)q);
        }
    }
}

// ---------------------------------------------------------------------------
extern "C" void kernel_launch(void* const* d_in, const int* in_sizes, int n_in,
                              void* d_out, int out_size, void* d_ws, size_t ws_size,
                              hipStream_t stream) {
    const float* x   = (const float*)d_in[0];
    const float* w1  = (const float*)d_in[1];
    const float* g1  = (const float*)d_in[2];
    const float* be1 = (const float*)d_in[3];
    const float* w2  = (const float*)d_in[4];
    const float* g2  = (const float*)d_in[5];
    const float* be2 = (const float*)d_in[6];
    const float* fw1 = (const float*)d_in[7];
    const float* fb1 = (const float*)d_in[8];
    const float* fw2 = (const float*)d_in[9];
    const float* fb2 = (const float*)d_in[10];
    const float* fw3 = (const float*)d_in[11];
    const float* fb3 = (const float*)d_in[12];

    char* ws = (char*)d_ws;
    double* stats1 = (double*)(ws + 0);      // 12 dbl
    double* mr1    = (double*)(ws + 256);    // 12 dbl
    double* stats2 = (double*)(ws + 512);    // 32 dbl
    double* mr2    = (double*)(ws + 768);    // 32 dbl
    float* qw1  = (float*)(ws + 1024);       // 150
    float* qw2  = (float*)(ws + 2048);       // 2400 (ends 11648)
    float* qfb1 = (float*)(ws + 12288);      // 120
    float* qfb2 = (float*)(ws + 12800);      // 84
    float* qfb3 = (float*)(ws + 13184);      // 10
    float* Wt1  = (float*)(ws + 16384);      // 400*128 (ends 221184)
    float* Wt2  = (float*)(ws + 221184);     // 120*128 (ends 282624)
    float* Wt3  = (float*)(ws + 282624);     // 84*16   (ends 288000)
    // big buffers (aliased by liveness)
    __hip_bfloat16* bufA = (__hip_bfloat16*)(ws + 294912);    // c1 [B,6,28,28] then c2 [B,16,10,10]
    __hip_bfloat16* bufB = (__hip_bfloat16*)(ws + 77365248);  // p1 [B,6,14,14] then p2 [B,400]
    __hip_bfloat16* bufC = (__hip_bfloat16*)(ws + 294912);    // a1 [B,120] (aliases dead bufA)
    __hip_bfloat16* bufD = (__hip_bfloat16*)(ws + 294912 + 2097152); // a2 [B,84]

    hipMemsetAsync(ws, 0, 1024, stream);

    kquant<<<1, 256, 0, stream>>>(w1, qw1, 150);
    kquant<<<(2400 + 255) / 256, 256, 0, stream>>>(w2, qw2, 2400);
    kquant<<<1, 256, 0, stream>>>(fb1, qfb1, 120);
    kquant<<<1, 256, 0, stream>>>(fb2, qfb2, 84);
    kquant<<<1, 256, 0, stream>>>(fb3, qfb3, 10);
    ktransq<<<(51200 + 255) / 256, 256, 0, stream>>>(fw1, Wt1, 400, 120, 128, 51200);
    ktransq<<<(15360 + 255) / 256, 256, 0, stream>>>(fw2, Wt2, 120, 84, 128, 15360);
    ktransq<<<(1344 + 255) / 256, 256, 0, stream>>>(fw3, Wt3, 84, 10, 16, 1344);

    // conv1 + fq -> bufA [B,6,28,28]   (3 images per block)
    kconv1<<<(BATCH + 2) / 3, 256, 0, stream>>>(x, qw1, bufA, BATCH);
    kstats<<<dim3(6, 256), 256, 0, stream>>>(bufA, stats1, 6, 784, BATCH);
    kfinal<<<1, 32, 0, stream>>>(stats1, mr1, 6, (double)BATCH * 784.0);
    {
        int total = BATCH * 6 * 14 * 14;
        kbnpool<<<(total + 255) / 256, 256, 0, stream>>>(bufA, mr1, g1, be1, bufB, 6, 28, 28, total);
    }
    // conv2 + fq -> bufA [B,16,10,10]  (2 images per block, 320 threads)
    kconv2<<<BATCH / 2, 320, 0, stream>>>(bufB, qw2, bufA);
    kstats<<<dim3(16, 256), 256, 0, stream>>>(bufA, stats2, 16, 100, BATCH);
    kfinal<<<1, 32, 0, stream>>>(stats2, mr2, 16, (double)BATCH * 100.0);
    {
        int total = BATCH * 16 * 5 * 5;
        kbnpool<<<(total + 255) / 256, 256, 0, stream>>>(bufA, mr2, g2, be2, bufB, 16, 10, 10, total);
    }
    // fc1 (+relu): [B,400] -> [B,120]
    kfc<400, 120, 128, 8><<<BATCH / 16, 256, 0, stream>>>(bufB, Wt1, qfb1, bufC, (float*)nullptr, 1);
    // fc2 (+relu): [B,120] -> [B,84]
    kfc<120, 84, 128, 8><<<BATCH / 16, 256, 0, stream>>>(bufC, Wt2, qfb2, bufD, (float*)nullptr, 1);
    // fc3: [B,84] -> [B,10] float out
    kfc<84, 10, 16, 1><<<BATCH / 16, 256, 0, stream>>>(bufD, Wt3, qfb3, (__hip_bfloat16*)nullptr, (float*)d_out, 0);
}